// Round 1
// baseline (512.946 us; speedup 1.0000x reference)
//
#include <hip/hip_runtime.h>
#include <math.h>

#define BB 16
#define CC 256
#define HH 128
#define WW 128
#define HWP (HH * WW)          // 16384 pixels per (b,c) plane
#define PLANE ((size_t)CC * HWP)

// ---------------------------------------------------------------------------
// Kernel 1: per-pixel channel mean + max.  One thread = 2 adjacent pixels
// (float2).  Lanes are contiguous in W -> every load is a coalesced
// 8B/lane x 64-lane = 512B transaction.  2048 waves total (8/CU).
// ---------------------------------------------------------------------------
__global__ __launch_bounds__(256) void reduce_kernel(
    const float* __restrict__ x,
    float* __restrict__ avg_map,
    float* __restrict__ max_map)
{
    int t  = blockIdx.x * blockDim.x + threadIdx.x;   // 0 .. B*HW/2-1
    int b  = t / (HWP / 2);
    int p2 = t % (HWP / 2);                           // float2 index in plane

    const float2* xp = (const float2*)(x + (size_t)b * PLANE) + p2;

    float2 s = make_float2(0.f, 0.f);
    float2 m = make_float2(-INFINITY, -INFINITY);
    #pragma unroll 8
    for (int c = 0; c < CC; ++c) {
        float2 v = xp[c * (HWP / 2)];
        s.x += v.x;               s.y += v.y;
        m.x = fmaxf(m.x, v.x);    m.y = fmaxf(m.y, v.y);
    }

    float2* ap = (float2*)(avg_map + (size_t)b * HWP) + p2;
    float2* mp = (float2*)(max_map + (size_t)b * HWP) + p2;
    *ap = make_float2(s.x * (1.f / 256.f), s.y * (1.f / 256.f));
    *mp = m;
}

// ---------------------------------------------------------------------------
// Kernel 2: 3x3 conv (2-in-ch, zero-pad) on the maps -> hardsigmoid ->
// broadcast multiply over 256 channels.  Same thread->pixel mapping as K1.
// Map reads hit L2/L3 (2 MB, just written).  Streams x once, writes out once.
// ---------------------------------------------------------------------------
__global__ __launch_bounds__(256) void apply_kernel(
    const float* __restrict__ x,
    const float* __restrict__ cw,      // [1][2][3][3]: cw[0..8]=avg, cw[9..17]=max
    const float* __restrict__ avg_map,
    const float* __restrict__ max_map,
    float* __restrict__ out)
{
    int t  = blockIdx.x * blockDim.x + threadIdx.x;
    int b  = t / (HWP / 2);
    int p2 = t % (HWP / 2);
    int h  = p2 / (WW / 2);
    int w0 = (p2 % (WW / 2)) * 2;

    // Weights: uniform address -> compiler scalarizes to s_load.
    float wa[9], wm[9];
    #pragma unroll
    for (int i = 0; i < 9; ++i) { wa[i] = cw[i]; wm[i] = cw[9 + i]; }

    const float* am = avg_map + (size_t)b * HWP;
    const float* mm = max_map + (size_t)b * HWP;

    float acc0 = 0.f, acc1 = 0.f;
    #pragma unroll
    for (int ki = 0; ki < 3; ++ki) {
        int hh = h + ki - 1;
        if (hh < 0 || hh >= HH) continue;
        #pragma unroll
        for (int kj = 0; kj < 3; ++kj) {
            float fa = wa[ki * 3 + kj];
            float fm = wm[ki * 3 + kj];
            int wwa = w0 + kj - 1;        // for pixel 0
            int wwb = w0 + 1 + kj - 1;    // for pixel 1
            if (wwa >= 0 && wwa < WW)
                acc0 += fa * am[hh * WW + wwa] + fm * mm[hh * WW + wwa];
            if (wwb >= 0 && wwb < WW)
                acc1 += fa * am[hh * WW + wwb] + fm * mm[hh * WW + wwb];
        }
    }

    // hardsigmoid: clip(y+3, 0, 6) / 6
    float a0 = fminf(fmaxf(acc0 + 3.f, 0.f), 6.f) * (1.f / 6.f);
    float a1 = fminf(fmaxf(acc1 + 3.f, 0.f), 6.f) * (1.f / 6.f);

    const float2* xp = (const float2*)(x + (size_t)b * PLANE) + p2;
    float2*       op = (float2*)(out + (size_t)b * PLANE) + p2;
    #pragma unroll 8
    for (int c = 0; c < CC; ++c) {
        float2 v = xp[c * (HWP / 2)];
        op[c * (HWP / 2)] = make_float2(v.x * a0, v.y * a1);
    }
}

extern "C" void kernel_launch(void* const* d_in, const int* in_sizes, int n_in,
                              void* d_out, int out_size, void* d_ws, size_t ws_size,
                              hipStream_t stream)
{
    const float* x  = (const float*)d_in[0];
    const float* cw = (const float*)d_in[1];
    float* out      = (float*)d_out;

    // Workspace: avg map then max map, each B*HW floats (1 MB each).
    float* avg_map = (float*)d_ws;
    float* max_map = avg_map + (size_t)BB * HWP;

    const int total_f2 = BB * HWP / 2;          // 131072 threads
    const int block    = 256;
    const int grid     = total_f2 / block;      // 512 blocks

    reduce_kernel<<<grid, block, 0, stream>>>(x, avg_map, max_map);
    apply_kernel <<<grid, block, 0, stream>>>(x, cw, avg_map, max_map, out);
}

// Round 3
// 497.371 us; speedup vs baseline: 1.0313x; 1.0313x over previous
//
#include <hip/hip_runtime.h>
#include <math.h>

#define BB 16
#define CC 256
#define HH 128
#define WW 128
#define HWP (HH * WW)               // 16384 pixels per (b,c) plane
#define P4  (HWP / 4)               // 4096 float4 per plane
#define PLANE ((size_t)CC * HWP)

typedef float f4 __attribute__((ext_vector_type(4)));

// ---------------------------------------------------------------------------
// K1: channel mean/max partial reduce, split-C=2 for TLP.
// thread -> (b, half, p4).  131072 threads = 512 blocks = 8 waves/CU.
// Each thread reduces 128 channels of one float4 pixel group.
// Loads are NORMAL (allocate in L2/L3) -- we want x resident for K2.
// ---------------------------------------------------------------------------
__global__ __launch_bounds__(256) void reduce_kernel(
    const float* __restrict__ x,
    float* __restrict__ psum,       // [2][B][HW] partial sums
    float* __restrict__ pmax)       // [2][B][HW] partial maxes
{
    int t    = blockIdx.x * 256 + threadIdx.x;
    int p4   = t & (P4 - 1);
    int half = (t >> 12) & 1;
    int b    = t >> 13;

    const f4* xp = (const f4*)(x + (size_t)b * PLANE + (size_t)half * 128 * HWP) + p4;

    f4 s = {0.f, 0.f, 0.f, 0.f};
    f4 m = {-INFINITY, -INFINITY, -INFINITY, -INFINITY};
    #pragma unroll 8
    for (int c = 0; c < 128; ++c) {
        f4 v = xp[c * P4];
        s.x += v.x; s.y += v.y; s.z += v.z; s.w += v.w;
        m.x = fmaxf(m.x, v.x); m.y = fmaxf(m.y, v.y);
        m.z = fmaxf(m.z, v.z); m.w = fmaxf(m.w, v.w);
    }

    f4* sp = (f4*)(psum + ((size_t)half * BB + b) * HWP) + p4;
    f4* mp = (f4*)(pmax + ((size_t)half * BB + b) * HWP) + p4;
    *sp = s;
    *mp = m;
}

// ---------------------------------------------------------------------------
// K_mid: combine halves + 3x3 conv (zero-pad, cross-correlation) +
// hardsigmoid -> attention map a[b,hw].  One thread per pixel.
// All reads hit L2 (partials = 4 MB, just written).  ~5 us.
// ---------------------------------------------------------------------------
__global__ __launch_bounds__(256) void conv_kernel(
    const float* __restrict__ cw,   // [1][2][3][3]: [0..8]=avg-ch, [9..17]=max-ch
    const float* __restrict__ psum,
    const float* __restrict__ pmax,
    float* __restrict__ amap)       // [B][HW] hardsigmoid output
{
    int t  = blockIdx.x * 256 + threadIdx.x;    // B*HW = 262144 threads
    int hw = t & (HWP - 1);
    int b  = t >> 14;
    int h  = hw >> 7;
    int w  = hw & (WW - 1);

    float wa[9], wm[9];
    #pragma unroll
    for (int i = 0; i < 9; ++i) { wa[i] = cw[i]; wm[i] = cw[9 + i]; }

    const float* s0 = psum + (size_t)b * HWP;
    const float* s1 = psum + ((size_t)BB + b) * HWP;
    const float* m0 = pmax + (size_t)b * HWP;
    const float* m1 = pmax + ((size_t)BB + b) * HWP;

    float acc = 0.f;
    #pragma unroll
    for (int ki = 0; ki < 3; ++ki) {
        int hh = h + ki - 1;
        if (hh < 0 || hh >= HH) continue;
        #pragma unroll
        for (int kj = 0; kj < 3; ++kj) {
            int ww = w + kj - 1;
            if (ww < 0 || ww >= WW) continue;
            int n = hh * WW + ww;
            float avg = (s0[n] + s1[n]) * (1.f / 256.f);
            float mx  = fmaxf(m0[n], m1[n]);
            acc += wa[ki * 3 + kj] * avg + wm[ki * 3 + kj] * mx;
        }
    }
    amap[t] = fminf(fmaxf(acc + 3.f, 0.f), 6.f) * (1.f / 6.f);
}

// ---------------------------------------------------------------------------
// K2: out = x * a.  thread -> (b, chan-group, p4); 262144 threads = 1024
// blocks = 16 waves/CU.  Channel loop DESCENDING (freshest-in-L3 first);
// nt loads for x (no re-allocate), nt stores for out (don't evict x from L3).
// ---------------------------------------------------------------------------
__global__ __launch_bounds__(256) void apply_kernel(
    const float* __restrict__ x,
    const float* __restrict__ amap,
    float* __restrict__ out)
{
    int t  = blockIdx.x * 256 + threadIdx.x;
    int p4 = t & (P4 - 1);
    int g  = (t >> 12) & 3;                    // 4 channel groups of 64
    int b  = t >> 14;

    f4 a = *((const f4*)(amap + (size_t)b * HWP) + p4);

    const f4* xp = (const f4*)(x   + (size_t)b * PLANE + (size_t)g * 64 * HWP) + p4;
    f4*       op = (f4*)      (out + (size_t)b * PLANE + (size_t)g * 64 * HWP) + p4;

    #pragma unroll 8
    for (int ci = 63; ci >= 0; --ci) {
        f4 v = __builtin_nontemporal_load(xp + ci * P4);
        f4 r;
        r.x = v.x * a.x; r.y = v.y * a.y; r.z = v.z * a.z; r.w = v.w * a.w;
        __builtin_nontemporal_store(r, op + ci * P4);
    }
}

extern "C" void kernel_launch(void* const* d_in, const int* in_sizes, int n_in,
                              void* d_out, int out_size, void* d_ws, size_t ws_size,
                              hipStream_t stream)
{
    const float* x  = (const float*)d_in[0];
    const float* cw = (const float*)d_in[1];
    float* out      = (float*)d_out;

    float* psum = (float*)d_ws;                          // 2 MB
    float* pmax = psum + (size_t)2 * BB * HWP;           // 2 MB
    float* amap = pmax + (size_t)2 * BB * HWP;           // 1 MB

    reduce_kernel<<<512,  256, 0, stream>>>(x, psum, pmax);
    conv_kernel  <<<1024, 256, 0, stream>>>(cw, psum, pmax, amap);
    apply_kernel <<<1024, 256, 0, stream>>>(x, amap, out);
}